// Round 12
// baseline (73.986 us; speedup 1.0000x reference)
//
#include <hip/hip_runtime.h>

#if defined(__has_builtin)
#  if __has_builtin(__builtin_amdgcn_exp2f)
#    define EXP2F(x) __builtin_amdgcn_exp2f(x)
#  else
#    define EXP2F(x) exp2f(x)
#  endif
#else
#  define EXP2F(x) exp2f(x)
#endif

constexpr int NPIX    = 262144;
constexpr int NC      = 1024;
constexpr int NG      = 256;
constexpr int THREADS = 512;            // 8 waves: 4 producers + 4 consumers
constexpr int PPB     = 512;            // pixels per block
constexpr int GRID    = NPIX / PPB;     // 512 blocks -> 2 blocks/CU

// ---- DPP helpers (VALU pipe, no lgkm) ----
template <int CTRL>
__device__ __forceinline__ float dpp_add(float v) {
    union { float f; int i; } u, t;
    u.f = v;
    t.i = __builtin_amdgcn_update_dpp(0, u.i, CTRL, 0xF, 0xF, true);
    return v + t.f;
}
template <int CTRL>
__device__ __forceinline__ float dpp_mov(float v) {
    union { float f; int i; } u, t;
    u.f = v;
    t.i = __builtin_amdgcn_update_dpp(0, u.i, CTRL, 0xF, 0xF, true);
    return t.f;
}
__device__ __forceinline__ float sum64_lane63(float v) {
    v = dpp_add<0xB1>(v);   // quad_perm xor1
    v = dpp_add<0x4E>(v);   // quad_perm xor2
    v = dpp_add<0x141>(v);  // row_half_mirror
    v = dpp_add<0x140>(v);  // row_mirror
    v = dpp_add<0x142>(v);  // row_bcast15
    v = dpp_add<0x143>(v);  // row_bcast31 -> lane 63 has wave total
    return v;
}
__device__ __forceinline__ float readlane63(float v) {
    union { float f; int i; } u; u.f = v;
    union { int i; float f; } r;
    r.i = __builtin_amdgcn_readlane(u.i, 63);
    return r.f;
}

// 4 coalesced full-row loads (1KB each) into a statically-named buffer
#define LOAD4(BUF, ABSROW)                                                   \
    _Pragma("unroll")                                                        \
    for (int j = 0; j < 4; ++j)                                              \
        BUF[j] = ((const float4*)(K + (size_t)((ABSROW) + j) * NG))[lane];

// reduce 4 buffered rows -> owner lanes capture raw sums (osx, osy)
#define RED4(BUF, REL)                                                       \
    _Pragma("unroll")                                                        \
    for (int j = 0; j < 4; ++j) {                                            \
        float sx = BUF[j].x * bb0.x + BUF[j].y * bb0.z;                      \
        float sy = BUF[j].x * bb0.y + BUF[j].y * bb0.w;                      \
        sx = fmaf(BUF[j].z, bb1.x, sx); sy = fmaf(BUF[j].z, bb1.y, sy);      \
        sx = fmaf(BUF[j].w, bb1.z, sx); sy = fmaf(BUF[j].w, bb1.w, sy);      \
        sx = sum64_lane63(sx); sy = sum64_lane63(sy);                        \
        const float tx = readlane63(sx);                                     \
        const float ty = readlane63(sy);                                     \
        if (lane == (REL) + j) { osx = tx; osy = ty; }                       \
    }

// N systolic B steps on (dxs, dys, acc) — pure VALU/trans + DPP
#define BSTEPS(N)                                                            \
    _Pragma("unroll")                                                        \
    for (int t = 0; t < (N); ++t) {                                          \
        float t0 = 0.f, t1 = 0.f, t2 = 0.f, t3 = 0.f;                        \
        _Pragma("unroll")                                                    \
        for (int j = 0; j < 4; ++j) {                                        \
            t0 = fmaf(rca[j].x, EXP2F(fmaf(dxs, rcx[j].x, dys * rcy[j].x)), t0); \
            t1 = fmaf(rca[j].y, EXP2F(fmaf(dxs, rcx[j].y, dys * rcy[j].y)), t1); \
            t2 = fmaf(rca[j].z, EXP2F(fmaf(dxs, rcx[j].z, dys * rcy[j].z)), t2); \
            t3 = fmaf(rca[j].w, EXP2F(fmaf(dxs, rcx[j].w, dys * rcy[j].w)), t3); \
        }                                                                    \
        acc += (t0 + t1) + (t2 + t3);                                        \
        dxs = dpp_mov<0x121>(dxs);   /* row_ror:1 */                         \
        dys = dpp_mov<0x121>(dys);                                           \
        acc = dpp_mov<0x121>(acc);                                           \
    }

__global__ __launch_bounds__(THREADS, 2)
void kbpa_pc(const float* __restrict__ alphas,
             const float* __restrict__ betas,
             const float* __restrict__ K,
             const float* __restrict__ pixels,
             const float* __restrict__ centers,
             const float* __restrict__ sdp2p,
             float* __restrict__ out)
{
    __shared__ float2 sxy_sh[PPB];      // raw row-sums handoff (4 KB)
    __shared__ int    flags[8];         // one per 64-px group

    const int tid  = threadIdx.x;
    const int lane = tid & 63;
    const int wv   = tid >> 6;

    // bijective XCD swizzle (512 % 8 == 0)
    const int bid  = (blockIdx.x & 7) * (GRID / 8) + (blockIdx.x >> 3);
    const int base = bid * PPB;

    if (tid < 8) flags[tid] = 0;        // replay-safe re-init
    __syncthreads();                    // only block-wide barrier

    const float f = -1.44269504088896340736f / (2.0f * sdp2p[0]);

    if (wv < 4) {
        // ================= producers: pure K streaming =================
        const float4* bf4 = (const float4*)betas;
        const float4 bb0 = bf4[2 * lane];
        const float4 bb1 = bf4[2 * lane + 1];

        #pragma unroll 1
        for (int chunk = 0; chunk < 2; ++chunk) {
            const int grp = wv * 2 + chunk;          // pixel group id 0..7
            const int r0  = base + grp * 64;         // 64 rows of this chunk
            float osx = 0.f, osy = 0.f;
            float4 kva[4], kvb[4];

            LOAD4(kva, r0)
            #pragma unroll 1
            for (int gg = 0; gg < 8; ++gg) {
                const int g = 2 * gg;
                LOAD4(kvb, r0 + (g + 1) * 4)
                RED4(kva, g * 4)
                if (gg < 7) { LOAD4(kva, r0 + (g + 2) * 4) }
                RED4(kvb, (g + 1) * 4)
            }
            sxy_sh[grp * 64 + lane] = make_float2(osx, osy);
            __threadfence_block();                   // drain ds_writes
            if (lane == 0) ((volatile int*)flags)[grp] = 1;
        }
    } else {
        // ================= consumers: systolic RBF =================
        const float m2f = -2.0f * f;
        float4 rcx[4], rcy[4], rca[4];
        {
            const float4* c4 = (const float4*)centers;
            const float4* a4 = (const float4*)alphas;
            #pragma unroll
            for (int j = 0; j < 4; ++j) {
                const float4 p0 = c4[lane * 8 + 2 * j];
                const float4 p1 = c4[lane * 8 + 2 * j + 1];
                rcx[j] = make_float4(p0.x, p0.z, p1.x, p1.z);
                rcy[j] = make_float4(p0.y, p0.w, p1.y, p1.w);
                const float4 al = a4[lane * 4 + j];
                rca[j].x = al.x * EXP2F(f * (rcx[j].x * rcx[j].x + rcy[j].x * rcy[j].x));
                rca[j].y = al.y * EXP2F(f * (rcx[j].y * rcx[j].y + rcy[j].y * rcy[j].y));
                rca[j].z = al.z * EXP2F(f * (rcx[j].z * rcx[j].z + rcy[j].z * rcy[j].z));
                rca[j].w = al.w * EXP2F(f * (rcx[j].w * rcx[j].w + rcy[j].w * rcy[j].w));
            }
        }

        const int b = wv - 4;
        #pragma unroll 1
        for (int grp = 2 * b; grp < 2 * b + 2; ++grp) {
            while (((volatile int*)flags)[grp] == 0)
                __builtin_amdgcn_s_sleep(2);
            __threadfence_block();

            const int p = base + grp * 64 + lane;
            const float2 s  = sxy_sh[grp * 64 + lane];
            const float2 px = ((const float2*)pixels)[p];
            const float dx = px.x - s.x;
            const float dy = px.y - s.y;

            float dxs = m2f * dx, dys = m2f * dy, acc = 0.f;
            #pragma unroll 1
            for (int round = 0; round < 4; ++round) {
                BSTEPS(16)
                const int sw = lane ^ ((round & 1) ? 32 : 16);
                dxs = __shfl(dxs, sw);
                dys = __shfl(dys, sw);
                acc = __shfl(acc, sw);
            }
            out[p] = acc * EXP2F(f * (dx * dx + dy * dy));
        }
    }
}

extern "C" void kernel_launch(void* const* d_in, const int* in_sizes, int n_in,
                              void* d_out, int out_size, void* d_ws, size_t ws_size,
                              hipStream_t stream)
{
    const float* alphas  = (const float*)d_in[0];
    const float* betas   = (const float*)d_in[1];
    const float* K       = (const float*)d_in[2];
    const float* pixels  = (const float*)d_in[3];
    const float* centers = (const float*)d_in[4];
    const float* sdp2    = (const float*)d_in[5];
    float* outp          = (float*)d_out;

    hipLaunchKernelGGL(kbpa_pc, dim3(GRID), dim3(THREADS), 0, stream,
                       alphas, betas, K, pixels, centers, sdp2, outp);
}

// Round 13
// 72.470 us; speedup vs baseline: 1.0209x; 1.0209x over previous
//
#include <hip/hip_runtime.h>

#if defined(__has_builtin)
#  if __has_builtin(__builtin_amdgcn_exp2f)
#    define EXP2F(x) __builtin_amdgcn_exp2f(x)
#  else
#    define EXP2F(x) exp2f(x)
#  endif
#else
#  define EXP2F(x) exp2f(x)
#endif

constexpr int NPIX  = 262144;
constexpr int NC    = 1024;
constexpr int NG    = 256;
constexpr int BLOCK = 256;                  // 4 waves; wave owns 128 px (2 chunks of 64)
constexpr int GRID  = NPIX / 512;           // 512 blocks

typedef float f32x4 __attribute__((ext_vector_type(4)));

// non-temporal 16B load (streaming K: no reuse, don't allocate in caches)
#if defined(__has_builtin) && __has_builtin(__builtin_nontemporal_load)
#  define NTLOAD4(P) __builtin_nontemporal_load((const f32x4*)(P))
#else
#  define NTLOAD4(P) (*(const f32x4*)(P))
#endif

// ---- DPP helpers (VALU pipe, no lgkm) ----
template <int CTRL>
__device__ __forceinline__ float dpp_add(float v) {
    union { float f; int i; } u, t;
    u.f = v;
    t.i = __builtin_amdgcn_update_dpp(0, u.i, CTRL, 0xF, 0xF, true);
    return v + t.f;
}
template <int CTRL>
__device__ __forceinline__ float dpp_mov(float v) {
    union { float f; int i; } u, t;
    u.f = v;
    t.i = __builtin_amdgcn_update_dpp(0, u.i, CTRL, 0xF, 0xF, true);
    return t.f;
}
__device__ __forceinline__ float sum64_lane63(float v) {
    v = dpp_add<0xB1>(v);   // quad_perm xor1
    v = dpp_add<0x4E>(v);   // quad_perm xor2
    v = dpp_add<0x141>(v);  // row_half_mirror
    v = dpp_add<0x140>(v);  // row_mirror
    v = dpp_add<0x142>(v);  // row_bcast15
    v = dpp_add<0x143>(v);  // row_bcast31 -> lane 63 has wave total
    return v;
}
__device__ __forceinline__ float readlane63(float v) {
    union { float f; int i; } u; u.f = v;
    union { int i; float f; } r;
    r.i = __builtin_amdgcn_readlane(u.i, 63);
    return r.f;
}

// 4 coalesced full-row non-temporal loads (1KB each) into a named buffer
#define LOAD4(BUF, ABSROW)                                                   \
    _Pragma("unroll")                                                        \
    for (int j = 0; j < 4; ++j)                                              \
        BUF[j] = NTLOAD4(K + (size_t)((ABSROW) + j) * NG + 4 * lane);

// reduce 4 buffered rows -> owner lanes capture (dx,dy)
#define RED4(BUF, REL, PX, DXO, DYO)                                         \
    _Pragma("unroll")                                                        \
    for (int j = 0; j < 4; ++j) {                                            \
        float sx = BUF[j][0] * bb0.x + BUF[j][1] * bb0.z;                    \
        float sy = BUF[j][0] * bb0.y + BUF[j][1] * bb0.w;                    \
        sx = fmaf(BUF[j][2], bb1.x, sx); sy = fmaf(BUF[j][2], bb1.y, sy);    \
        sx = fmaf(BUF[j][3], bb1.z, sx); sy = fmaf(BUF[j][3], bb1.w, sy);    \
        sx = sum64_lane63(sx); sy = sum64_lane63(sy);                        \
        const float tx = readlane63(sx);                                     \
        const float ty = readlane63(sy);                                     \
        if (lane == (REL) + j) { DXO = PX.x - tx; DYO = PX.y - ty; }         \
    }

// N systolic B steps on state (dxs, dys, acc) — pure VALU/trans + DPP
#define BSTEPS(N)                                                            \
    _Pragma("unroll")                                                        \
    for (int t = 0; t < (N); ++t) {                                          \
        float t0 = 0.f, t1 = 0.f, t2 = 0.f, t3 = 0.f;                        \
        _Pragma("unroll")                                                    \
        for (int j = 0; j < 4; ++j) {                                        \
            t0 = fmaf(rca[j].x, EXP2F(fmaf(dxs, rcx[j].x, dys * rcy[j].x)), t0); \
            t1 = fmaf(rca[j].y, EXP2F(fmaf(dxs, rcx[j].y, dys * rcy[j].y)), t1); \
            t2 = fmaf(rca[j].z, EXP2F(fmaf(dxs, rcx[j].z, dys * rcy[j].z)), t2); \
            t3 = fmaf(rca[j].w, EXP2F(fmaf(dxs, rcx[j].w, dys * rcy[j].w)), t3); \
        }                                                                    \
        acc += (t0 + t1) + (t2 + t3);                                        \
        dxs = dpp_mov<0x121>(dxs);   /* row_ror:1 */                         \
        dys = dpp_mov<0x121>(dys);                                           \
        acc = dpp_mov<0x121>(acc);                                           \
    }

__global__ __launch_bounds__(BLOCK, 2)
void kbpa_pipe(const float* __restrict__ alphas,
               const float* __restrict__ betas,
               const float* __restrict__ K,
               const float* __restrict__ pixels,
               const float* __restrict__ centers,
               const float* __restrict__ sdp2p,
               float* __restrict__ out)
{
    const int lane = threadIdx.x & 63;
    const int wave = threadIdx.x >> 6;

    // bijective XCD swizzle (gridDim.x = 512, divisible by 8)
    const int cpx = GRID / 8;
    const int bid = (blockIdx.x & 7) * cpx + (blockIdx.x >> 3);

    const float f   = -1.44269504088896340736f / (2.0f * sdp2p[0]);
    const float m2f = -2.0f * f;

    // ---- register-resident centers: lane holds c = lane*16 .. +15 ----
    float4 rcx[4], rcy[4], rca[4];
    {
        const float4* c4 = (const float4*)centers;
        const float4* a4 = (const float4*)alphas;
        #pragma unroll
        for (int j = 0; j < 4; ++j) {
            const float4 p0 = c4[lane * 8 + 2 * j];
            const float4 p1 = c4[lane * 8 + 2 * j + 1];
            rcx[j] = make_float4(p0.x, p0.z, p1.x, p1.z);
            rcy[j] = make_float4(p0.y, p0.w, p1.y, p1.w);
            const float4 al = a4[lane * 4 + j];
            rca[j].x = al.x * EXP2F(f * (rcx[j].x * rcx[j].x + rcy[j].x * rcy[j].x));
            rca[j].y = al.y * EXP2F(f * (rcx[j].y * rcx[j].y + rcy[j].y * rcy[j].y));
            rca[j].z = al.z * EXP2F(f * (rcx[j].z * rcx[j].z + rcy[j].z * rcy[j].z));
            rca[j].w = al.w * EXP2F(f * (rcx[j].w * rcx[j].w + rcy[j].w * rcy[j].w));
        }
    }

    // betas fragment: lane covers K cols 4l..4l+3 -> betas rows 4l..4l+3
    const float4* bf4 = (const float4*)betas;
    const float4 bb0 = bf4[2 * lane];
    const float4 bb1 = bf4[2 * lane + 1];

    const int w0 = bid * 512 + wave * 128;       // chunk0: w0.., chunk1: w0+64..
    const int w1 = w0 + 64;
    const float2 px0 = ((const float2*)pixels)[w0 + lane];
    const float2 px1 = ((const float2*)pixels)[w1 + lane];

    float dx0 = 0.f, dy0 = 0.f, dx1 = 0.f, dy1 = 0.f;
    f32x4 kva[4], kvb[4];

    // ---- prologue: A(chunk0), double-buffered (>=4 loads always in flight) ----
    LOAD4(kva, w0 + 0)
    #pragma unroll 1
    for (int gg = 0; gg < 8; ++gg) {
        const int g = 2 * gg;
        LOAD4(kvb, w0 + (g + 1) * 4)
        RED4(kva, g * 4, px0, dx0, dy0)
        if (gg < 7) { LOAD4(kva, w0 + (g + 2) * 4) }
        RED4(kvb, (g + 1) * 4, px0, dx0, dy0)
    }

    // ---- steady: A(chunk1) streams (double-buffered) while B(chunk0) on VALU ----
    float dxs = m2f * dx0, dys = m2f * dy0, acc = 0.f;
    LOAD4(kva, w1 + 0)
    #pragma unroll 1
    for (int gg = 0; gg < 8; ++gg) {
        const int g = 2 * gg;
        LOAD4(kvb, w1 + (g + 1) * 4)
        BSTEPS(4)
        RED4(kva, g * 4, px1, dx1, dy1)
        if (gg < 7) { LOAD4(kva, w1 + (g + 2) * 4) }
        BSTEPS(4)
        RED4(kvb, (g + 1) * 4, px1, dx1, dy1)
        if (gg & 1) {                       // after t = 16,32,48,64: row swap
            const int sw = lane ^ ((gg & 2) ? 32 : 16);
            dxs = __shfl(dxs, sw);
            dys = __shfl(dys, sw);
            acc = __shfl(acc, sw);
        }
    }
    out[w0 + lane] = acc * EXP2F(f * (dx0 * dx0 + dy0 * dy0));

    // ---- epilogue: B(chunk1) ----
    dxs = m2f * dx1; dys = m2f * dy1; acc = 0.f;
    #pragma unroll 1
    for (int round = 0; round < 4; ++round) {
        BSTEPS(16)
        const int sw = lane ^ ((round & 1) ? 32 : 16);
        dxs = __shfl(dxs, sw);
        dys = __shfl(dys, sw);
        acc = __shfl(acc, sw);
    }
    out[w1 + lane] = acc * EXP2F(f * (dx1 * dx1 + dy1 * dy1));
}

extern "C" void kernel_launch(void* const* d_in, const int* in_sizes, int n_in,
                              void* d_out, int out_size, void* d_ws, size_t ws_size,
                              hipStream_t stream)
{
    const float* alphas  = (const float*)d_in[0];
    const float* betas   = (const float*)d_in[1];
    const float* K       = (const float*)d_in[2];
    const float* pixels  = (const float*)d_in[3];
    const float* centers = (const float*)d_in[4];
    const float* sdp2    = (const float*)d_in[5];
    float* outp          = (float*)d_out;

    hipLaunchKernelGGL(kbpa_pipe, dim3(GRID), dim3(BLOCK), 0, stream,
                       alphas, betas, K, pixels, centers, sdp2, outp);
}